// Round 1
// baseline (290.518 us; speedup 1.0000x reference)
//
#include <hip/hip_runtime.h>

// Problem constants
#define VV 50000
#define EE 512       // embedding dim (= GEMM K)
#define SS 1024      // conv filters (= GEMM N per weight half)
#define BB 64
#define LL 256
#define NTOK (BB*LL)         // 16384 token rows (GEMM M)
#define XROWS_PAD (NTOK + 8) // padded rows so last-tile staging never faults

typedef __attribute__((ext_vector_type(8))) __bf16 bf16x8;
typedef __attribute__((ext_vector_type(4))) float f32x4;
typedef __attribute__((ext_vector_type(4))) unsigned short us4;

static __device__ __forceinline__ unsigned short f2bf(float f) {
    unsigned int u = __float_as_uint(f);
    u += 0x7FFFu + ((u >> 16) & 1u);   // round-to-nearest-even
    return (unsigned short)(u >> 16);
}

static __device__ __forceinline__ void glds16(const void* g, void* l) {
    __builtin_amdgcn_global_load_lds(
        (const __attribute__((address_space(1))) unsigned int*)g,
        (__attribute__((address_space(3))) unsigned int*)l,
        16, 0, 0);
}

// Kernel 1: gather embedding rows by token index, convert fp32 -> bf16.
// grid = NTOK blocks, 128 threads; each thread converts 4 elements.
__global__ void gather_bf16_kernel(const int* __restrict__ inputs,
                                   const float* __restrict__ emb,
                                   unsigned short* __restrict__ Xbf) {
    const int t = blockIdx.x;
    const int idx = inputs[t];
    const int tid = threadIdx.x;
    const float4 v = *(const float4*)(emb + (size_t)idx * EE + tid * 4);
    us4 o;
    o.x = f2bf(v.x); o.y = f2bf(v.y); o.z = f2bf(v.z); o.w = f2bf(v.w);
    *(us4*)(Xbf + (size_t)t * EE + tid * 4) = o;
}

// Kernel 2: Wc fp32 -> bf16 (layout preserved: [S][2E] row-major).
// grid = 1024 blocks x 256 threads x 4 elems = 1M elements.
__global__ void wc_bf16_kernel(const float* __restrict__ Wc,
                               unsigned short* __restrict__ Wbf) {
    const int i = (blockIdx.x * 256 + threadIdx.x) * 4;
    const float4 v = *(const float4*)(Wc + i);
    us4 o;
    o.x = f2bf(v.x); o.y = f2bf(v.y); o.z = f2bf(v.z); o.w = f2bf(v.w);
    *(us4*)(Wbf + i) = o;
}

// Kernel 3: fused dual GEMM + sliding-window add + masked max-pool epilogue.
// conv[t,s] = X[t]·Wc[s,0:512] + X[t+1]·Wc[s,512:1024]  (valid when (t&255)!=255)
// pre[b,s] = max over valid t in batch b, stored as order-preserving uint via atomicMax.
// Tile: TM=128 tokens x TN=64 s-cols, BK=64. 4 waves; wave grid 2(m) x 2(n),
// each wave: 64 rows x 32 cols, dual accumulators (4x2x2 f32x4 = 64 acc regs).
__global__ __launch_bounds__(256, 2)
void conv_gemm_kernel(const unsigned short* __restrict__ Xbf,
                      const unsigned short* __restrict__ Wbf,
                      unsigned int* __restrict__ pre) {
    __shared__ unsigned short sX[136 * 64];  // rows 0..128 used (+1 for shift)
    __shared__ unsigned short sW[128 * 64];  // [h*64+s_local][k], h=0:Wc1 h=1:Wc2

    const int tid = threadIdx.x;
    const int w = tid >> 6;          // wave 0..3
    const int lane = tid & 63;
    const int wx = w >> 1;           // n-half (0/1) -> cols wx*32..+32
    const int wy = w & 1;            // m-half (0/1) -> rows wy*64..+64
    const int m0 = blockIdx.y * 128; // token-tile base (never crosses batch: 128|256)
    const int s0 = blockIdx.x * 64;  // filter-tile base

    f32x4 accA[4][2], accB[4][2];
    for (int mt = 0; mt < 4; ++mt)
        for (int nt = 0; nt < 2; ++nt) {
            accA[mt][nt] = (f32x4){0.f, 0.f, 0.f, 0.f};
            accB[mt][nt] = (f32x4){0.f, 0.f, 0.f, 0.f};
        }

    const int lrow = lane >> 3;        // 0..7 (row within a wave's 8-row stripe)
    const int lcol = (lane & 7) * 8;   // element offset (8 bf16 = 16B chunks)

    for (int kt = 0; kt < 8; ++kt) {
        const int k0 = kt * 64;
        // --- stage: X rows 0..127 and both W halves (32 rows per round) ---
        for (int r = 0; r < 4; ++r) {
            const int xrow = r * 32 + w * 8;
            glds16(Xbf + (size_t)(m0 + xrow + lrow) * EE + k0 + lcol,
                   (char*)sX + xrow * 128);
            const int wrow = r * 32 + w * 8 + lrow;      // 0..127
            const int h = wrow >> 6, sl = wrow & 63;
            glds16(Wbf + (size_t)(s0 + sl) * 1024 + h * 512 + k0 + lcol,
                   (char*)sW + (r * 32 + w * 8) * 128);
        }
        if (w == 0) {  // X rows 128..135 (only 128 used; global side padded)
            glds16(Xbf + (size_t)(m0 + 128 + lrow) * EE + k0 + lcol,
                   (char*)sX + 128 * 128);
        }
        __syncthreads();

        // --- compute: 2 MFMA K-steps of 32 ---
        for (int ks = 0; ks < 64; ks += 32) {
            const int kf = ks + (lane >> 4) * 8;
            const int mrb = wy * 64 + (lane & 15);
            const int nrb = wx * 32 + (lane & 15);
            bf16x8 aA[4], aB[4], b1f[2], b2f[2];
            for (int mt = 0; mt < 4; ++mt) {
                aA[mt] = *(const bf16x8*)(sX + (mrb + mt * 16) * 64 + kf);
                aB[mt] = *(const bf16x8*)(sX + (mrb + mt * 16 + 1) * 64 + kf);
            }
            for (int nt = 0; nt < 2; ++nt) {
                b1f[nt] = *(const bf16x8*)(sW + (nrb + nt * 16) * 64 + kf);
                b2f[nt] = *(const bf16x8*)(sW + (64 + nrb + nt * 16) * 64 + kf);
            }
            for (int mt = 0; mt < 4; ++mt)
                for (int nt = 0; nt < 2; ++nt) {
                    accA[mt][nt] = __builtin_amdgcn_mfma_f32_16x16x32_bf16(
                        aA[mt], b1f[nt], accA[mt][nt], 0, 0, 0);
                    accB[mt][nt] = __builtin_amdgcn_mfma_f32_16x16x32_bf16(
                        aB[mt], b2f[nt], accB[mt][nt], 0, 0, 0);
                }
        }
        __syncthreads();
    }

    // --- epilogue: conv = accA + accB, mask l==255, column max, atomicMax ---
    // C/D layout (16x16): col = lane&15, row = (lane>>4)*4 + reg
    const int quad = lane >> 4;
    const int b = m0 >> 8;  // batch index
    for (int nt = 0; nt < 2; ++nt) {
        float cmax = -3.4e38f;
        for (int mt = 0; mt < 4; ++mt) {
            const int rbase = m0 + wy * 64 + mt * 16 + quad * 4;
            for (int r = 0; r < 4; ++r) {
                const float v = accA[mt][nt][r] + accB[mt][nt][r];
                const bool valid = (((rbase + r) & 255) != 255);
                cmax = valid ? fmaxf(cmax, v) : cmax;
            }
        }
        cmax = fmaxf(cmax, __shfl_xor(cmax, 16));
        cmax = fmaxf(cmax, __shfl_xor(cmax, 32));
        if (lane < 16) {
            const unsigned int u = __float_as_uint(cmax);
            const unsigned int e = (u & 0x80000000u) ? ~u : (u | 0x80000000u);
            atomicMax(pre + b * SS + s0 + wx * 32 + nt * 16 + lane, e);
        }
    }
}

// Kernel 4: sigmoid(max + bc) -> h = sig·W1^T + b1 -> logits -> log_softmax.
// grid = 64 blocks (one per batch row), 256 threads (4 waves).
__global__ void classifier_kernel(const unsigned int* __restrict__ pre,
                                  const float* __restrict__ bc,
                                  const float* __restrict__ W1,
                                  const float* __restrict__ b1,
                                  const float* __restrict__ W2,
                                  const float* __restrict__ b2,
                                  float* __restrict__ out) {
    __shared__ float ssig[SS];
    __shared__ float sh[52];
    const int b = blockIdx.x;
    const int tid = threadIdx.x;
    for (int s = tid; s < SS; s += 256) {
        const unsigned int e = pre[b * SS + s];
        const unsigned int u = (e & 0x80000000u) ? (e & 0x7FFFFFFFu) : ~e;
        const float x = __uint_as_float(u) + bc[s];
        ssig[s] = 1.0f / (1.0f + expf(-x));
    }
    __syncthreads();
    const int w = tid >> 6, lane = tid & 63;
    for (int j = w; j < 50; j += 4) {
        float p = 0.f;
        for (int s = lane; s < SS; s += 64) p += ssig[s] * W1[j * SS + s];
        for (int off = 32; off; off >>= 1) p += __shfl_xor(p, off);
        if (lane == 0) sh[j] = p + b1[j];
    }
    __syncthreads();
    if (tid == 0) {
        float l0 = b2[0], l1 = b2[1];
        for (int j = 0; j < 50; ++j) { l0 += sh[j] * W2[j]; l1 += sh[j] * W2[50 + j]; }
        const float m = fmaxf(l0, l1);
        const float lse = m + logf(expf(l0 - m) + expf(l1 - m));
        out[b * 2 + 0] = l0 - lse;
        out[b * 2 + 1] = l1 - lse;
    }
}

extern "C" void kernel_launch(void* const* d_in, const int* in_sizes, int n_in,
                              void* d_out, int out_size, void* d_ws, size_t ws_size,
                              hipStream_t stream) {
    const int*   inputs = (const int*)  d_in[0];
    const float* emb    = (const float*)d_in[1];
    const float* Wc     = (const float*)d_in[2];
    const float* bc     = (const float*)d_in[3];
    const float* W1     = (const float*)d_in[4];
    const float* b1     = (const float*)d_in[5];
    const float* W2     = (const float*)d_in[6];
    const float* b2     = (const float*)d_in[7];
    float* out = (float*)d_out;

    // ws layout
    unsigned short* Xbf = (unsigned short*)d_ws;                 // XROWS_PAD*512 bf16
    unsigned short* Wbf = Xbf + (size_t)XROWS_PAD * EE;          // 1024*1024 bf16
    unsigned int*   pre = (unsigned int*)(Wbf + (size_t)SS * 1024); // 64*1024 u32

    gather_bf16_kernel<<<NTOK, 128, 0, stream>>>(inputs, emb, Xbf);
    wc_bf16_kernel<<<1024, 256, 0, stream>>>(Wc, Wbf);
    hipMemsetAsync(pre, 0, (size_t)BB * SS * sizeof(unsigned int), stream);
    dim3 grid(SS / 64, NTOK / 128);  // (16, 128)
    conv_gemm_kernel<<<grid, 256, 0, stream>>>(Xbf, Wbf, pre);
    classifier_kernel<<<BB, 256, 0, stream>>>(pre, bc, W1, b1, W2, b2, out);
}

// Round 2
// 209.252 us; speedup vs baseline: 1.3884x; 1.3884x over previous
//
#include <hip/hip_runtime.h>

// Problem constants
#define VV 50000
#define EE 512       // embedding dim (= GEMM K per half)
#define SS 1024      // conv filters (= GEMM N)
#define BB 64
#define LL 256
#define NTOK (BB*LL)         // 16384 token rows (GEMM M)
#define XROWS_PAD (NTOK + 8) // padded rows so last-tile staging never faults

typedef __attribute__((ext_vector_type(8))) __bf16 bf16x8;
typedef __attribute__((ext_vector_type(4))) float f32x4;
typedef __attribute__((ext_vector_type(4))) unsigned short us4;

static __device__ __forceinline__ unsigned short f2bf(float f) {
    unsigned int u = __float_as_uint(f);
    u += 0x7FFFu + ((u >> 16) & 1u);   // round-to-nearest-even
    return (unsigned short)(u >> 16);
}

static __device__ __forceinline__ void glds16(const void* g, void* l) {
    __builtin_amdgcn_global_load_lds(
        (const __attribute__((address_space(1))) unsigned int*)g,
        (__attribute__((address_space(3))) unsigned int*)l,
        16, 0, 0);
}

// Kernel 1: gather embedding rows by token index, convert fp32 -> bf16.
// grid = NTOK blocks, 128 threads; each thread converts 4 elements.
__global__ void gather_bf16_kernel(const int* __restrict__ inputs,
                                   const float* __restrict__ emb,
                                   unsigned short* __restrict__ Xbf) {
    const int t = blockIdx.x;
    const int idx = inputs[t];
    const int tid = threadIdx.x;
    const float4 v = *(const float4*)(emb + (size_t)idx * EE + tid * 4);
    us4 o;
    o.x = f2bf(v.x); o.y = f2bf(v.y); o.z = f2bf(v.z); o.w = f2bf(v.w);
    *(us4*)(Xbf + (size_t)t * EE + tid * 4) = o;
}

// Kernel 2: Wc fp32 -> bf16 (layout preserved: [S][2E] row-major) + zero `pre`.
// grid = 1024 blocks x 256 threads x 4 elems = 1M elements.
__global__ void wc_bf16_kernel(const float* __restrict__ Wc,
                               unsigned short* __restrict__ Wbf,
                               unsigned int* __restrict__ pre) {
    const int i = (blockIdx.x * 256 + threadIdx.x) * 4;
    const float4 v = *(const float4*)(Wc + i);
    us4 o;
    o.x = f2bf(v.x); o.y = f2bf(v.y); o.z = f2bf(v.z); o.w = f2bf(v.w);
    *(us4*)(Wbf + i) = o;
    if (blockIdx.x < BB) {  // zero the pool buffer (encodes -inf): 64 x 1024 words
        uint4 z = {0u, 0u, 0u, 0u};
        *(uint4*)(pre + blockIdx.x * SS + threadIdx.x * 4) = z;
    }
}

// Kernel 3: fused dual-half GEMM + sliding-window add + masked max-pool epilogue.
// conv[t,s] = X[t]·Wc[s,0:512] + X[t+1]·Wc[s,512:1024]  (valid when (t&255)!=255)
// Both halves accumulate into ONE accumulator (they sum anyway).
// Tile: TM=128 tokens x TN=128 s-cols, BK=64, 8 K-chunks. 4 waves in 2x2;
// each wave: 64 rows x 64 cols, acc = f32x4[4][4] (64 regs).
// ds_read:MFMA = 16:32 per K32-step = 0.5 (m97 ratio).
__global__ __launch_bounds__(256, 2)
void conv_gemm_kernel(const unsigned short* __restrict__ Xbf,
                      const unsigned short* __restrict__ Wbf,
                      unsigned int* __restrict__ pre) {
    __shared__ unsigned short sX[136 * 64];  // rows 0..128 used (+1 for shift)
    __shared__ unsigned short sW[256 * 64];  // [h*128 + s_local][k], h=0:Wc1 h=1:Wc2

    const int tid = threadIdx.x;
    const int w = tid >> 6;          // wave 0..3
    const int lane = tid & 63;
    const int wx = w & 1;            // n-half -> cols wx*64..+64
    const int wy = w >> 1;           // m-half -> rows wy*64..+64
    const int m0 = blockIdx.y * 128; // token-tile base (never crosses batch: 128|256)
    const int s0 = blockIdx.x * 128; // filter-tile base

    f32x4 acc[4][4];
    #pragma unroll
    for (int mt = 0; mt < 4; ++mt)
        #pragma unroll
        for (int nt = 0; nt < 4; ++nt)
            acc[mt][nt] = (f32x4){0.f, 0.f, 0.f, 0.f};

    const int lrow = lane >> 3;        // 0..7 (row within an 8-row staging stripe)
    const int lcol = (lane & 7) * 8;   // element offset (8 bf16 = 16B chunks)
    const int quad = lane >> 4;
    const int l15 = lane & 15;

    for (int kt = 0; kt < 8; ++kt) {
        const int k0 = kt * 64;
        // --- stage: X rows 0..135 (17 calls), W rows 0..255 (32 calls) ---
        #pragma unroll
        for (int i = 0; i < 4; ++i) {
            const int c = w + 4 * i;                       // 0..15
            glds16(Xbf + (size_t)(m0 + c * 8 + lrow) * EE + k0 + lcol,
                   (char*)sX + c * 1024);
        }
        if (w == 0) {
            glds16(Xbf + (size_t)(m0 + 128 + lrow) * EE + k0 + lcol,
                   (char*)sX + 16 * 1024);
        }
        #pragma unroll
        for (int i = 0; i < 8; ++i) {
            const int c = w + 4 * i;                       // 0..31
            const int wrow = c * 8 + lrow;                 // 0..255
            const int h = wrow >> 7, sl = wrow & 127;
            glds16(Wbf + (size_t)(s0 + sl) * 1024 + h * 512 + k0 + lcol,
                   (char*)sW + c * 1024);
        }
        __syncthreads();

        // --- compute: 2 MFMA K-steps of 32 ---
        #pragma unroll
        for (int ks = 0; ks < 64; ks += 32) {
            const int kf = ks + quad * 8;
            const int mrb = wy * 64 + l15;
            const int nrb = wx * 64 + l15;
            bf16x8 aA[4], aB[4], b1f[4], b2f[4];
            #pragma unroll
            for (int mt = 0; mt < 4; ++mt) {
                aA[mt] = *(const bf16x8*)(sX + (mrb + mt * 16) * 64 + kf);
                aB[mt] = *(const bf16x8*)(sX + (mrb + mt * 16 + 1) * 64 + kf);
            }
            #pragma unroll
            for (int nt = 0; nt < 4; ++nt) {
                b1f[nt] = *(const bf16x8*)(sW + (nrb + nt * 16) * 64 + kf);
                b2f[nt] = *(const bf16x8*)(sW + (128 + nrb + nt * 16) * 64 + kf);
            }
            #pragma unroll
            for (int mt = 0; mt < 4; ++mt)
                #pragma unroll
                for (int nt = 0; nt < 4; ++nt) {
                    acc[mt][nt] = __builtin_amdgcn_mfma_f32_16x16x32_bf16(
                        aA[mt], b1f[nt], acc[mt][nt], 0, 0, 0);
                    acc[mt][nt] = __builtin_amdgcn_mfma_f32_16x16x32_bf16(
                        aB[mt], b2f[nt], acc[mt][nt], 0, 0, 0);
                }
        }
        __syncthreads();
    }

    // --- epilogue: mask l==255, column max, LDS-combine wy halves, atomicMax ---
    // C/D layout (16x16): col = lane&15, row = (lane>>4)*4 + reg
    const int b = m0 >> 8;  // batch index
    float* smax = (float*)sX;  // reuse: [2][128]
    #pragma unroll
    for (int nt = 0; nt < 4; ++nt) {
        float cmax = -3.4e38f;
        #pragma unroll
        for (int mt = 0; mt < 4; ++mt) {
            const int rbase = m0 + wy * 64 + mt * 16 + quad * 4;
            #pragma unroll
            for (int r = 0; r < 4; ++r) {
                const float v = acc[mt][nt][r];
                const bool valid = (((rbase + r) & 255) != 255);
                cmax = valid ? fmaxf(cmax, v) : cmax;
            }
        }
        cmax = fmaxf(cmax, __shfl_xor(cmax, 16));
        cmax = fmaxf(cmax, __shfl_xor(cmax, 32));
        if (lane < 16) smax[wy * 128 + wx * 64 + nt * 16 + lane] = cmax;
    }
    __syncthreads();
    if (tid < 128) {
        const float m = fmaxf(smax[tid], smax[128 + tid]);
        const unsigned int u = __float_as_uint(m);
        const unsigned int e = (u & 0x80000000u) ? ~u : (u | 0x80000000u);
        atomicMax(pre + b * SS + s0 + tid, e);
    }
}

// Kernel 4: sigmoid(max + bc) -> h = sig·W1^T + b1 -> logits -> log_softmax.
// grid = 64 blocks (one per batch row), 1024 threads (16 waves).
// Vectorized float4 dots, wave-parallel logits tail.
__global__ __launch_bounds__(1024)
void classifier_kernel(const unsigned int* __restrict__ pre,
                       const float* __restrict__ bc,
                       const float* __restrict__ W1,
                       const float* __restrict__ b1,
                       const float* __restrict__ W2,
                       const float* __restrict__ b2,
                       float* __restrict__ out) {
    __shared__ float ssig[SS];
    __shared__ float sh[64];
    const int b = blockIdx.x;
    const int tid = threadIdx.x;
    {
        const unsigned int e = pre[b * SS + tid];
        const unsigned int u = (e & 0x80000000u) ? (e & 0x7FFFFFFFu) : ~e;
        const float x = __uint_as_float(u) + bc[tid];
        ssig[tid] = 1.0f / (1.0f + __expf(-x));
    }
    if (tid >= 50 && tid < 64) sh[tid] = 0.f;
    __syncthreads();
    const int w = tid >> 6, lane = tid & 63;
    const float4* sp = (const float4*)ssig;  // 256 float4
    for (int j = w; j < 50; j += 16) {
        const float4* wp = (const float4*)(W1 + j * SS);
        float p = 0.f;
        #pragma unroll
        for (int i = 0; i < 4; ++i) {
            const float4 a = sp[lane + i * 64];
            const float4 g = wp[lane + i * 64];
            p += a.x * g.x + a.y * g.y + a.z * g.z + a.w * g.w;
        }
        #pragma unroll
        for (int off = 32; off; off >>= 1) p += __shfl_xor(p, off);
        if (lane == 0) sh[j] = p + b1[j];
    }
    __syncthreads();
    if (w == 0) {
        const float hj = (lane < 50) ? sh[lane] : 0.f;
        const float w2a = (lane < 50) ? W2[lane] : 0.f;
        const float w2b = (lane < 50) ? W2[50 + lane] : 0.f;
        float l0 = hj * w2a, l1 = hj * w2b;
        #pragma unroll
        for (int off = 32; off; off >>= 1) {
            l0 += __shfl_xor(l0, off);
            l1 += __shfl_xor(l1, off);
        }
        if (lane == 0) {
            l0 += b2[0]; l1 += b2[1];
            const float m = fmaxf(l0, l1);
            const float lse = m + logf(expf(l0 - m) + expf(l1 - m));
            out[b * 2 + 0] = l0 - lse;
            out[b * 2 + 1] = l1 - lse;
        }
    }
}

extern "C" void kernel_launch(void* const* d_in, const int* in_sizes, int n_in,
                              void* d_out, int out_size, void* d_ws, size_t ws_size,
                              hipStream_t stream) {
    const int*   inputs = (const int*)  d_in[0];
    const float* emb    = (const float*)d_in[1];
    const float* Wc     = (const float*)d_in[2];
    const float* bc     = (const float*)d_in[3];
    const float* W1     = (const float*)d_in[4];
    const float* b1     = (const float*)d_in[5];
    const float* W2     = (const float*)d_in[6];
    const float* b2     = (const float*)d_in[7];
    float* out = (float*)d_out;

    // ws layout
    unsigned short* Xbf = (unsigned short*)d_ws;                 // XROWS_PAD*512 bf16
    unsigned short* Wbf = Xbf + (size_t)XROWS_PAD * EE;          // 1024*1024 bf16
    unsigned int*   pre = (unsigned int*)(Wbf + (size_t)SS * 1024); // 64*1024 u32

    gather_bf16_kernel<<<NTOK, 128, 0, stream>>>(inputs, emb, Xbf);
    wc_bf16_kernel<<<1024, 256, 0, stream>>>(Wc, Wbf, pre);
    dim3 grid(SS / 128, NTOK / 128);  // (8, 128) = 1024 blocks
    conv_gemm_kernel<<<grid, 256, 0, stream>>>(Xbf, Wbf, pre);
    classifier_kernel<<<BB, 1024, 0, stream>>>(pre, bc, W1, b1, W2, b2, out);
}

// Round 3
// 199.116 us; speedup vs baseline: 1.4590x; 1.0509x over previous
//
#include <hip/hip_runtime.h>

// Problem constants
#define VV 50000
#define EE 512       // embedding dim (= GEMM K per half)
#define SS 1024      // conv filters (= GEMM N)
#define BB 64
#define LL 256
#define NTOK (BB*LL)         // 16384 token rows (GEMM M)
#define XROWS_PAD (NTOK + 8) // padded rows so last-tile staging never faults

typedef __attribute__((ext_vector_type(8))) __bf16 bf16x8;
typedef __attribute__((ext_vector_type(4))) float f32x4;
typedef __attribute__((ext_vector_type(4))) unsigned short us4;

static __device__ __forceinline__ unsigned short f2bf(float f) {
    unsigned int u = __float_as_uint(f);
    u += 0x7FFFu + ((u >> 16) & 1u);   // round-to-nearest-even
    return (unsigned short)(u >> 16);
}

static __device__ __forceinline__ void glds16(const void* g, void* l) {
    __builtin_amdgcn_global_load_lds(
        (const __attribute__((address_space(1))) unsigned int*)g,
        (__attribute__((address_space(3))) unsigned int*)l,
        16, 0, 0);
}

// Kernel 1: gather embedding rows by token index, convert fp32 -> bf16.
__global__ void gather_bf16_kernel(const int* __restrict__ inputs,
                                   const float* __restrict__ emb,
                                   unsigned short* __restrict__ Xbf) {
    const int t = blockIdx.x;
    const int idx = inputs[t];
    const int tid = threadIdx.x;
    const float4 v = *(const float4*)(emb + (size_t)idx * EE + tid * 4);
    us4 o;
    o.x = f2bf(v.x); o.y = f2bf(v.y); o.z = f2bf(v.z); o.w = f2bf(v.w);
    *(us4*)(Xbf + (size_t)t * EE + tid * 4) = o;
}

// Kernel 2: Wc fp32 -> bf16 (layout preserved: [S][2E] row-major) + zero `pre`.
__global__ void wc_bf16_kernel(const float* __restrict__ Wc,
                               unsigned short* __restrict__ Wbf,
                               unsigned int* __restrict__ pre) {
    const int i = (blockIdx.x * 256 + threadIdx.x) * 4;
    const float4 v = *(const float4*)(Wc + i);
    us4 o;
    o.x = f2bf(v.x); o.y = f2bf(v.y); o.z = f2bf(v.z); o.w = f2bf(v.w);
    *(us4*)(Wbf + i) = o;
    if (blockIdx.x < BB) {  // zero pool buffer (encodes -inf): 64 x 1024 words
        uint4 z = {0u, 0u, 0u, 0u};
        *(uint4*)(pre + blockIdx.x * SS + threadIdx.x * 4) = z;
    }
}

// Kernel 3: fused dual-half GEMM + sliding-window add + masked max-pool epilogue.
// conv[t,s] = X[t]·Wc[s,0:512] + X[t+1]·Wc[s,512:1024]  (valid when (t&255)!=255)
// Tile: TM=128 x TN=128, BK=64. 4 waves 2x2, each 64x64, acc f32x4[4][4].
//
// LDS layout: stripes of 8 rows x 8 chunks (chunk = 16 B = 8 bf16), with
// XOR column swizzle: physical chunk c of row r holds LOGICAL chunk c^(r&7).
// glds16 pins LDS dest = stripe + lane*16, so the swizzle is applied on the
// global-source address (lane fetches logical chunk (lane&7)^(lane>>3)).
// Fragment reads use chunk cb^(row&7): rows 0..7 spread over all 32 banks ->
// 2 lanes/bank-group = conflict-free (was 16 lanes/group = 2x LDS slowdown).
__global__ __launch_bounds__(256, 3)
void conv_gemm_kernel(const unsigned short* __restrict__ Xbf,
                      const unsigned short* __restrict__ Wbf,
                      unsigned int* __restrict__ pre) {
    __shared__ unsigned short sX[136 * 64];  // rows 0..128 used (+1 for shift)
    __shared__ unsigned short sW[256 * 64];  // [h*128 + s_local][k]

    const int tid = threadIdx.x;
    const int w = tid >> 6;          // wave 0..3
    const int lane = tid & 63;
    const int wx = w & 1;            // n-half -> cols wx*64..+64
    const int wy = w >> 1;           // m-half -> rows wy*64..+64
    const int m0 = blockIdx.y * 128; // token-tile base (never crosses batch: 128|256)
    const int s0 = blockIdx.x * 128; // filter-tile base

    f32x4 acc[4][4];
    #pragma unroll
    for (int mt = 0; mt < 4; ++mt)
        #pragma unroll
        for (int nt = 0; nt < 4; ++nt)
            acc[mt][nt] = (f32x4){0.f, 0.f, 0.f, 0.f};

    const int lrow = lane >> 3;                   // row within 8-row stripe
    const int lcolsw = (((lane & 7) ^ lrow) * 8); // swizzled global column (elems)
    const int quad = lane >> 4;
    const int l15 = lane & 15;
    const int swA  = l15 & 7;        // row&7 for aA fragment rows
    const int swA1 = (l15 + 1) & 7;  // row&7 for aB (shifted) fragment rows

    for (int kt = 0; kt < 8; ++kt) {
        const int k0 = kt * 64;
        // --- stage: X stripes 0..16 (17 calls), W stripes 0..31 ---
        #pragma unroll
        for (int i = 0; i < 4; ++i) {
            const int c = w + 4 * i;                       // 0..15
            glds16(Xbf + (size_t)(m0 + c * 8 + lrow) * EE + k0 + lcolsw,
                   (char*)sX + c * 1024);
        }
        if (w == 0) {
            glds16(Xbf + (size_t)(m0 + 128 + lrow) * EE + k0 + lcolsw,
                   (char*)sX + 16 * 1024);
        }
        #pragma unroll
        for (int i = 0; i < 8; ++i) {
            const int c = w + 4 * i;                       // 0..31
            const int wrow = c * 8 + lrow;                 // 0..255
            const int h = wrow >> 7, sl = wrow & 127;
            glds16(Wbf + (size_t)(s0 + sl) * 1024 + h * 512 + k0 + lcolsw,
                   (char*)sW + c * 1024);
        }
        __syncthreads();

        // --- compute: 2 MFMA K-steps of 32 ---
        #pragma unroll
        for (int ks = 0; ks < 64; ks += 32) {
            const int cb = (ks >> 3) + quad;   // logical chunk 0..7
            const int mrb = wy * 64 + l15;
            const int nrb = wx * 64 + l15;
            bf16x8 aA[4], aB[4];
            #pragma unroll
            for (int mt = 0; mt < 4; ++mt) {
                aA[mt] = *(const bf16x8*)(sX + (mrb + mt * 16) * 64 + ((cb ^ swA) << 3));
                aB[mt] = *(const bf16x8*)(sX + (mrb + 1 + mt * 16) * 64 + ((cb ^ swA1) << 3));
            }
            #pragma unroll
            for (int nt = 0; nt < 4; ++nt) {
                const bf16x8 b1f = *(const bf16x8*)(sW + (nrb + nt * 16) * 64 + ((cb ^ swA) << 3));
                const bf16x8 b2f = *(const bf16x8*)(sW + (128 + nrb + nt * 16) * 64 + ((cb ^ swA) << 3));
                #pragma unroll
                for (int mt = 0; mt < 4; ++mt) {
                    acc[mt][nt] = __builtin_amdgcn_mfma_f32_16x16x32_bf16(
                        aA[mt], b1f, acc[mt][nt], 0, 0, 0);
                    acc[mt][nt] = __builtin_amdgcn_mfma_f32_16x16x32_bf16(
                        aB[mt], b2f, acc[mt][nt], 0, 0, 0);
                }
            }
        }
        __syncthreads();
    }

    // --- epilogue: mask l==255, column max, LDS-combine wy halves, atomicMax ---
    // C/D layout (16x16): col = lane&15, row = (lane>>4)*4 + reg
    const int b = m0 >> 8;  // batch index
    float* smax = (float*)sX;  // reuse: [2][128]
    #pragma unroll
    for (int nt = 0; nt < 4; ++nt) {
        float cmax = -3.4e38f;
        #pragma unroll
        for (int mt = 0; mt < 4; ++mt) {
            const int rbase = m0 + wy * 64 + mt * 16 + quad * 4;
            #pragma unroll
            for (int r = 0; r < 4; ++r) {
                const float v = acc[mt][nt][r];
                const bool valid = (((rbase + r) & 255) != 255);
                cmax = valid ? fmaxf(cmax, v) : cmax;
            }
        }
        cmax = fmaxf(cmax, __shfl_xor(cmax, 16));
        cmax = fmaxf(cmax, __shfl_xor(cmax, 32));
        if (lane < 16) smax[wy * 128 + wx * 64 + nt * 16 + lane] = cmax;
    }
    __syncthreads();
    if (tid < 128) {
        const float m = fmaxf(smax[tid], smax[128 + tid]);
        const unsigned int u = __float_as_uint(m);
        const unsigned int e = (u & 0x80000000u) ? ~u : (u | 0x80000000u);
        atomicMax(pre + b * SS + s0 + tid, e);
    }
}

// Kernel 4: sigmoid(max + bc) -> h = sig·W1^T + b1 -> logits -> log_softmax.
__global__ __launch_bounds__(1024)
void classifier_kernel(const unsigned int* __restrict__ pre,
                       const float* __restrict__ bc,
                       const float* __restrict__ W1,
                       const float* __restrict__ b1,
                       const float* __restrict__ W2,
                       const float* __restrict__ b2,
                       float* __restrict__ out) {
    __shared__ float ssig[SS];
    __shared__ float sh[64];
    const int b = blockIdx.x;
    const int tid = threadIdx.x;
    {
        const unsigned int e = pre[b * SS + tid];
        const unsigned int u = (e & 0x80000000u) ? (e & 0x7FFFFFFFu) : ~e;
        const float x = __uint_as_float(u) + bc[tid];
        ssig[tid] = 1.0f / (1.0f + __expf(-x));
    }
    if (tid >= 50 && tid < 64) sh[tid] = 0.f;
    __syncthreads();
    const int w = tid >> 6, lane = tid & 63;
    const float4* sp = (const float4*)ssig;  // 256 float4
    for (int j = w; j < 50; j += 16) {
        const float4* wp = (const float4*)(W1 + j * SS);
        float p = 0.f;
        #pragma unroll
        for (int i = 0; i < 4; ++i) {
            const float4 a = sp[lane + i * 64];
            const float4 g = wp[lane + i * 64];
            p += a.x * g.x + a.y * g.y + a.z * g.z + a.w * g.w;
        }
        #pragma unroll
        for (int off = 32; off; off >>= 1) p += __shfl_xor(p, off);
        if (lane == 0) sh[j] = p + b1[j];
    }
    __syncthreads();
    if (w == 0) {
        const float hj = (lane < 50) ? sh[lane] : 0.f;
        const float w2a = (lane < 50) ? W2[lane] : 0.f;
        const float w2b = (lane < 50) ? W2[50 + lane] : 0.f;
        float l0 = hj * w2a, l1 = hj * w2b;
        #pragma unroll
        for (int off = 32; off; off >>= 1) {
            l0 += __shfl_xor(l0, off);
            l1 += __shfl_xor(l1, off);
        }
        if (lane == 0) {
            l0 += b2[0]; l1 += b2[1];
            const float m = fmaxf(l0, l1);
            const float lse = m + logf(expf(l0 - m) + expf(l1 - m));
            out[b * 2 + 0] = l0 - lse;
            out[b * 2 + 1] = l1 - lse;
        }
    }
}

extern "C" void kernel_launch(void* const* d_in, const int* in_sizes, int n_in,
                              void* d_out, int out_size, void* d_ws, size_t ws_size,
                              hipStream_t stream) {
    const int*   inputs = (const int*)  d_in[0];
    const float* emb    = (const float*)d_in[1];
    const float* Wc     = (const float*)d_in[2];
    const float* bc     = (const float*)d_in[3];
    const float* W1     = (const float*)d_in[4];
    const float* b1     = (const float*)d_in[5];
    const float* W2     = (const float*)d_in[6];
    const float* b2     = (const float*)d_in[7];
    float* out = (float*)d_out;

    // ws layout
    unsigned short* Xbf = (unsigned short*)d_ws;                 // XROWS_PAD*512 bf16
    unsigned short* Wbf = Xbf + (size_t)XROWS_PAD * EE;          // 1024*1024 bf16
    unsigned int*   pre = (unsigned int*)(Wbf + (size_t)SS * 1024); // 64*1024 u32

    gather_bf16_kernel<<<NTOK, 128, 0, stream>>>(inputs, emb, Xbf);
    wc_bf16_kernel<<<1024, 256, 0, stream>>>(Wc, Wbf, pre);
    dim3 grid(SS / 128, NTOK / 128);  // (8, 128) = 1024 blocks
    conv_gemm_kernel<<<grid, 256, 0, stream>>>(Xbf, Wbf, pre);
    classifier_kernel<<<BB, 1024, 0, stream>>>(pre, bc, W1, b1, W2, b2, out);
}